// Round 4
// baseline (4081.723 us; speedup 1.0000x reference)
//
#include <hip/hip_runtime.h>
#include <hip/hip_bf16.h>
#include <cstdint>
#include <cstddef>

typedef unsigned short u16;
typedef __attribute__((ext_vector_type(8))) short short8;
typedef __attribute__((ext_vector_type(4))) float float4v;

__device__ __forceinline__ float b2f(u16 u) {
  union { unsigned int i; float f; } v; v.i = ((unsigned int)u) << 16; return v.f;
}
__device__ __forceinline__ u16 f2b(float f) {
  union { float f; unsigned int i; } v; v.f = f;
  unsigned int r = v.i + 0x7fffu + ((v.i >> 16) & 1u);
  return (u16)(r >> 16);
}
__device__ __forceinline__ float silu_f(float v) { return v / (1.f + __expf(-v)); }
__device__ __forceinline__ float softplus_f(float v) {
  return (v > 0.f) ? v + log1pf(__expf(-v)) : log1pf(__expf(v));
}
// dtype-adaptive raw-input load (element index): f32!=0 -> fp32, else bf16
__device__ __forceinline__ u16 ldx(const void* src, size_t i, int f32) {
  return f32 ? f2b(((const float*)src)[i]) : ((const u16*)src)[i];
}

#define GLD_LDS16(g, s) __builtin_amdgcn_global_load_lds( \
    (const __attribute__((address_space(1))) void*)(g),   \
    (__attribute__((address_space(3))) void*)(s), 16, 0, 0)

// Dtype probe: the low u16 of fp32 words is ~uniform bits (bf16-exponent
// field uniform 0..255, ~11% land in [100,127]); the low u16 of a bf16 pair
// is a genuine bf16 (~N(0,0.02)) whose exponent is ~always in [100,127].
// flag: 0 = bf16 inputs, 1 = fp32 inputs.
__global__ void probe_kernel(const void* w, int* flag)
{
  __shared__ int cnt;
  if (threadIdx.x == 0) cnt = 0;
  __syncthreads();
  const unsigned int* p = (const unsigned int*)w;
  int c = 0;
  for (int i = threadIdx.x; i < 1024; i += 256) {
    unsigned int lo = p[i] & 0xFFFFu;
    int e = (int)((lo >> 7) & 0xFFu);
    c += (e >= 100 && e <= 127) ? 1 : 0;
  }
  atomicAdd(&cnt, c);
  __syncthreads();
  if (threadIdx.x == 0) *flag = (cnt >= 512) ? 0 : 1;
}

// Convert the 20 small-parameter tensors into one canonical bf16 block.
struct SegTable { const void* src[20]; int off[20]; int cnt[20]; };
__global__ void convert_params(SegTable t, u16* dst, const int* flag)
{
  const int s = blockIdx.x;
  const int f32 = *flag;
  u16* d = dst + t.off[s];
  const int n = t.cnt[s];
  for (int i = threadIdx.x; i < n; i += 256) d[i] = ldx(t.src[s], i, f32);
}

// Adaptive convert with element offset: dst[i] = (bf16)src[eoff + i].
__global__ void convert_off(const void* __restrict__ src, size_t eoff,
                            u16* __restrict__ dst, size_t n,
                            const int* __restrict__ flag)
{
  const size_t i = (size_t)blockIdx.x * 256 + threadIdx.x;
  if (i < n) dst[i] = ldx(src, eoff + i, *flag);
}

// ---------------------------------------------------------------------------
// C[M,N] = epilogue(A[M,K] @ Bt[N,K]^T + bias). 128x128x32 tile, 4 waves,
// m97-lineage core. A, Bt are canonical bf16 (ws buffers).
// EPI: 0 bf16 store; 1 silu->bf16; 2 outf[idx]+=v; 3 (v+add[idx])->bf16;
//      5 fp32 store; 7 flag-dependent final store (fp32 if *dtf else bf16).
// ---------------------------------------------------------------------------
template<int EPI>
__global__ __launch_bounds__(256)
void gemm_bt(const u16* __restrict__ A, const u16* __restrict__ Bt,
             const u16* __restrict__ bias, u16* __restrict__ outb,
             float* __restrict__ outf, const u16* __restrict__ add,
             int M, int N, int K, const int* dtf)
{
  __shared__ u16 As[128 * 32];
  __shared__ u16 Bs[128 * 32];
  const int tid  = threadIdx.x;
  const int lane = tid & 63;
  const int wave = tid >> 6;
  const int quad = lane >> 4;
  const int l15  = lane & 15;
  const int wr = (wave >> 1) << 6;
  const int wc = (wave & 1) << 6;
  const int bm = blockIdx.y * 128;
  const int bn = blockIdx.x * 128;

  const int r0 = tid >> 2;
  const int c0 = (tid & 3) << 3;
  const u16* Ab = A  + (size_t)(bm + r0) * K + c0;
  const u16* Bb = Bt + (size_t)(bn + r0) * K + c0;
  char* sA = (char*)As + tid * 16;
  char* sB = (char*)Bs + tid * 16;

  float4v acc[4][4] = {};

  for (int k0 = 0; k0 < K; k0 += 32) {
    GLD_LDS16(Ab + k0,                  sA);
    GLD_LDS16(Ab + (size_t)64 * K + k0, sA + 4096);
    GLD_LDS16(Bb + k0,                  sB);
    GLD_LDS16(Bb + (size_t)64 * K + k0, sB + 4096);
    __syncthreads();

    short8 aF[4], bF[4];
#pragma unroll
    for (int i = 0; i < 4; ++i) {
      aF[i] = *(const short8*)(As + (wr + i * 16 + l15) * 32 + quad * 8);
      bF[i] = *(const short8*)(Bs + (wc + i * 16 + l15) * 32 + quad * 8);
    }
#pragma unroll
    for (int mi = 0; mi < 4; ++mi)
#pragma unroll
      for (int ni = 0; ni < 4; ++ni)
        acc[mi][ni] = __builtin_amdgcn_mfma_f32_16x16x32_bf16(aF[mi], bF[ni], acc[mi][ni], 0, 0, 0);
    __syncthreads();
  }

  float bv[4];
#pragma unroll
  for (int ni = 0; ni < 4; ++ni)
    bv[ni] = bias ? b2f(bias[bn + wc + ni * 16 + l15]) : 0.f;

  const int f32out = (EPI == 7) ? *dtf : 0;

#pragma unroll
  for (int mi = 0; mi < 4; ++mi) {
#pragma unroll
    for (int ni = 0; ni < 4; ++ni) {
      const int m = bm + wr + mi * 16 + quad * 4;
      const int n = bn + wc + ni * 16 + l15;
#pragma unroll
      for (int r = 0; r < 4; ++r) {
        float v = acc[mi][ni][r] + bv[ni];
        size_t idx = (size_t)(m + r) * N + n;
        if (EPI == 0)      outb[idx] = f2b(v);
        else if (EPI == 1) outb[idx] = f2b(silu_f(v));
        else if (EPI == 2) outf[idx] = outf[idx] + v;
        else if (EPI == 3) outb[idx] = f2b(v + b2f(add[idx]));
        else if (EPI == 5) outf[idx] = v;
        else if (EPI == 7) { if (f32out) outf[idx] = v; else outb[idx] = f2b(v); }
      }
    }
  }
}

// LayerNorm over D=512, fp32 in -> bf16 out. One wave per row.
__global__ __launch_bounds__(256)
void ln_kernel(const float* __restrict__ in, u16* __restrict__ out,
               const u16* __restrict__ w, const u16* __restrict__ b)
{
  const int lane = threadIdx.x & 63;
  const int row  = blockIdx.x * 4 + (threadIdx.x >> 6);
  const float* x = in + (size_t)row * 512;
  float v[8], s = 0.f;
#pragma unroll
  for (int i = 0; i < 8; ++i) { v[i] = x[i * 64 + lane]; s += v[i]; }
#pragma unroll
  for (int m = 1; m < 64; m <<= 1) s += __shfl_xor(s, m);
  const float mean = s * (1.f / 512.f);
  float s2 = 0.f;
#pragma unroll
  for (int i = 0; i < 8; ++i) { float d = v[i] - mean; s2 += d * d; }
#pragma unroll
  for (int m = 1; m < 64; m <<= 1) s2 += __shfl_xor(s2, m);
  const float rs = rsqrtf(s2 * (1.f / 512.f) + 1e-5f);
  u16* o = out + (size_t)row * 512;
#pragma unroll
  for (int i = 0; i < 8; ++i) {
    int c = i * 64 + lane;
    o[c] = f2b((v[i] - mean) * rs * b2f(w[c]) + b2f(b[c]));
  }
}

// Timestep sinusoidal embedding: out[b,0:256]=cos, out[b,256:512]=sin.
__global__ void temb_kernel(const int* __restrict__ ts, u16* __restrict__ out)
{
  const int b = blockIdx.x, d = threadIdx.x;  // 256 threads
  float t = (float)ts[b];
  float fr = __expf(-9.210340371976184f * (float)d * (1.f / 256.f));
  float a = t * fr;
  out[(size_t)b * 512 + d]       = f2b(cosf(a));
  out[(size_t)b * 512 + 256 + d] = f2b(sinf(a));
}

// xproj = silu(xp[:, :1024] * conv_center + conv_b) + cp
__global__ __launch_bounds__(256)
void fuse_conv_kernel(const u16* __restrict__ xp, const u16* __restrict__ cw,
                      const u16* __restrict__ cb, const u16* __restrict__ cp,
                      u16* __restrict__ xpr)
{
  const int idx = blockIdx.x * 256 + threadIdx.x;  // over R*1024
  const int b = idx >> 10, c = idx & 1023;
  float v = b2f(xp[(size_t)b * 2048 + c]) * b2f(cw[c * 3 + 1]) + b2f(cb[c]);
  xpr[idx] = f2b(silu_f(v) + b2f(cp[idx]));
}

// Selective-scan collapse (L=1):
// y = (dot(Bp,Cp)*mean(softplus(dt))*mean(x) + x*Dp) * silu(gate).
__global__ __launch_bounds__(256)
void scan_kernel(const u16* __restrict__ dtbc, const u16* __restrict__ xproj,
                 const u16* __restrict__ xp, const u16* __restrict__ dt_b,
                 const u16* __restrict__ dt_bias, const u16* __restrict__ B_b,
                 const u16* __restrict__ C_b, const u16* __restrict__ Dp,
                 u16* __restrict__ y)
{
  const int lane = threadIdx.x & 63;
  const int row  = blockIdx.x * 4 + (threadIdx.x >> 6);
  const u16* drow = dtbc + (size_t)row * 1152;
  const u16* xrow = xproj + (size_t)row * 1024;
  float xv[16], sdt = 0.f, sx = 0.f;
#pragma unroll
  for (int i = 0; i < 16; ++i) {
    int c = i * 64 + lane;
    sdt += softplus_f(b2f(drow[c]) + b2f(dt_b[c]) + b2f(dt_bias[c]));
    xv[i] = b2f(xrow[c]);
    sx += xv[i];
  }
  float bp  = b2f(drow[1024 + lane]) + b2f(B_b[lane]);
  float cpv = b2f(drow[1088 + lane]) + b2f(C_b[lane]);
  float dot = bp * cpv;
#pragma unroll
  for (int m = 1; m < 64; m <<= 1) {
    sdt += __shfl_xor(sdt, m);
    sx  += __shfl_xor(sx, m);
    dot += __shfl_xor(dot, m);
  }
  const float scal = dot * (sdt * (1.f / 1024.f)) * (sx * (1.f / 1024.f));
  const u16* grow = xp + (size_t)row * 2048 + 1024;
  u16* yrow = y + (size_t)row * 1024;
#pragma unroll
  for (int i = 0; i < 16; ++i) {
    int c = i * 64 + lane;
    yrow[c] = f2b((scal + xv[i] * b2f(Dp[c])) * silu_f(b2f(grow[c])));
  }
}

// 32x32-tiled transpose from a RAW input (adaptive): dst[n][k] = src[k][n].
__global__ void transpose_kernel(const void* __restrict__ src, u16* __restrict__ dst,
                                 int K, int N, const int* flag)
{
  __shared__ u16 t[32][33];
  const int f32 = *flag;
  const int n0 = blockIdx.x * 32, k0 = blockIdx.y * 32;
  const int tx = threadIdx.x, ty = threadIdx.y;
#pragma unroll
  for (int i = 0; i < 32; i += 8)
    t[ty + i][tx] = ldx(src, (size_t)(k0 + ty + i) * N + n0 + tx, f32);
  __syncthreads();
#pragma unroll
  for (int i = 0; i < 32; i += 8)
    dst[(size_t)(n0 + ty + i) * K + k0 + tx] = t[tx][ty + i];
}

// Segmented adaptive transpose of one layer's weights into wbuf; layer slice
// selected by ELEMENT offset eoff (per-dtype width applied inside ldx).
// grid.x = 3200. wbuf (u16 elems): inprojT @0 [2048,512]; condpT @1048576
// [1024,512]; outT @1572864 [512,1024]; dtbcT @2097152 [1152,1024].
__global__ void transpose_layer(const void* __restrict__ ipw, const void* __restrict__ cpw,
                                const void* __restrict__ ow, const void* __restrict__ dtw,
                                const void* __restrict__ bw, const void* __restrict__ cw_,
                                int layer, u16* __restrict__ wbuf, const int* flag)
{
  __shared__ u16 t[32][33];
  const int f32 = *flag;
  int tb_ = blockIdx.x;
  const void* src; u16* dst; int K, N; size_t eoff;
  if (tb_ < 1024)      { src = ipw; dst = wbuf;           K = 512;  N = 2048; eoff = (size_t)layer * 512 * 2048; }
  else if (tb_ < 1536) { tb_ -= 1024; src = cpw; dst = wbuf + 1048576; K = 512;  N = 1024; eoff = (size_t)layer * 512 * 1024; }
  else if (tb_ < 2048) { tb_ -= 1536; src = ow;  dst = wbuf + 1572864; K = 1024; N = 512;  eoff = (size_t)layer * 1024 * 512; }
  else if (tb_ < 3072) { tb_ -= 2048; src = dtw; dst = wbuf + 2097152; K = 1024; N = 1024; eoff = (size_t)layer * 1024 * 1024; }
  else if (tb_ < 3136) { tb_ -= 3072; src = bw;  dst = wbuf + 2097152 + 1024 * 1024; K = 1024; N = 64; eoff = (size_t)layer * 1024 * 64; }
  else                 { tb_ -= 3136; src = cw_; dst = wbuf + 2097152 + 1088 * 1024; K = 1024; N = 64; eoff = (size_t)layer * 1024 * 64; }
  const int nt = tb_ % (N / 32), kt = tb_ / (N / 32);
  const int n0 = nt * 32, k0 = kt * 32;
  const int tx = threadIdx.x, ty = threadIdx.y;
#pragma unroll
  for (int i = 0; i < 32; i += 8)
    t[ty + i][tx] = ldx(src, eoff + (size_t)(k0 + ty + i) * N + n0 + tx, f32);
  __syncthreads();
#pragma unroll
  for (int i = 0; i < 32; i += 8)
    dst[(size_t)(n0 + ty + i) * K + k0 + tx] = t[tx][ty + i];
}

// Param-block offsets (u16 elems)
enum {
  P_in_b = 0, P_t_b1 = 512, P_t_b2 = 2560, P_c_b1 = 3072, P_c_b2 = 3584,
  P_op_b = 4096, P_on_w = 5120, P_on_b = 5632, P_norm_w = 6144,
  P_norm_b = 10240, P_inproj_b = 14336, P_condp_b = 30720, P_out_b = 38912,
  P_conv_w = 43008, P_conv_b = 67584, P_dt_b = 75776, P_dt_bias = 83968,
  P_B_b = 92160, P_C_b = 92672, P_Dp = 93184, P_TOTAL = 101376
};

extern "C" void kernel_launch(void* const* d_in, const int* in_sizes, int n_in,
                              void* d_out, int out_size, void* d_ws, size_t ws_size,
                              hipStream_t stream)
{
  const void* x        = d_in[0];
  const int*  tstep    = (const int*)d_in[1];
  const void* cond_in  = d_in[2];
  const void* in_w     = d_in[3];
  const void* in_b     = d_in[4];
  const void* t_w1     = d_in[5];
  const void* t_b1     = d_in[6];
  const void* t_w2     = d_in[7];
  const void* t_b2     = d_in[8];
  const void* c_w1     = d_in[9];
  const void* c_b1     = d_in[10];
  const void* c_w2     = d_in[11];
  const void* c_b2     = d_in[12];
  const void* norm_w   = d_in[13];
  const void* norm_b   = d_in[14];
  const void* inproj_w = d_in[15];
  const void* inproj_b = d_in[16];
  const void* conv_w   = d_in[17];
  const void* conv_b   = d_in[18];
  const void* dt_w     = d_in[19];
  const void* dt_b     = d_in[20];
  const void* dt_bias  = d_in[21];
  /* d_in[22] = A_log: dead at L=1 (h0 == 0, single scan step) */
  const void* Dp       = d_in[23];
  const void* B_w      = d_in[24];
  const void* B_b      = d_in[25];
  const void* C_w      = d_in[26];
  const void* C_b      = d_in[27];
  const void* condp_w  = d_in[28];
  const void* condp_b  = d_in[29];
  const void* out_w    = d_in[30];
  const void* out_b    = d_in[31];
  const void* on_w     = d_in[32];
  const void* on_b     = d_in[33];
  const void* op_w     = d_in[34];
  const void* op_b     = d_in[35];

  const int B = 16384;
  const size_t WB = (size_t)3276800 * 2;  // 6.25 MiB weight scratch

  // per-row ws bytes: h 2048 + hn 1024 + cond 1024 + xp 4096 + cp 2048 +
  // xproj 2048 + dtbc 2304 + xbf 2048 + cbf 256 = 16896
  int c = 128;
  for (int cc = 1; cc <= 128; cc <<= 1) {
    size_t R = (size_t)B / cc;
    if (WB + 262144 + R * 16896 + 65536 <= ws_size) { c = cc; break; }
  }
  const int R = B / c;

  char* p = (char*)d_ws;
  auto alloc = [&](size_t bytes) {
    char* r = p; p += ((bytes + 255) & ~(size_t)255); return r;
  };
  int*   flag  = (int*)alloc(4);
  u16*   prm   = (u16*)alloc((size_t)P_TOTAL * 2);
  u16*   wbuf  = (u16*)alloc(WB);
  float* h     = (float*)alloc((size_t)R * 512 * 4);
  u16*   hn    = (u16*)alloc((size_t)R * 512 * 2);
  u16*   cond  = (u16*)alloc((size_t)R * 512 * 2);
  u16*   xp    = (u16*)alloc((size_t)R * 2048 * 2);
  u16*   cp    = (u16*)alloc((size_t)R * 1024 * 2);
  u16*   xproj = (u16*)alloc((size_t)R * 1024 * 2);
  u16*   dtbc  = (u16*)alloc((size_t)R * 1152 * 2);
  u16*   xbf   = (u16*)alloc((size_t)R * 1024 * 2);
  u16*   cbf   = (u16*)alloc((size_t)R * 128 * 2);

  // ---- dtype probe + canonical bf16 params (once per launch) ----
  probe_kernel<<<1, 256, 0, stream>>>(in_w, flag);
  {
    SegTable t;
    const void* s[20] = { in_b, t_b1, t_b2, c_b1, c_b2, op_b, on_w, on_b,
                          norm_w, norm_b, inproj_b, condp_b, out_b, conv_w,
                          conv_b, dt_b, dt_bias, B_b, C_b, Dp };
    const int o[20] = { P_in_b, P_t_b1, P_t_b2, P_c_b1, P_c_b2, P_op_b, P_on_w,
                        P_on_b, P_norm_w, P_norm_b, P_inproj_b, P_condp_b,
                        P_out_b, P_conv_w, P_conv_b, P_dt_b, P_dt_bias, P_B_b,
                        P_C_b, P_Dp };
    const int n[20] = { 512, 2048, 512, 512, 512, 1024, 512, 512, 4096, 4096,
                        16384, 8192, 4096, 24576, 8192, 8192, 8192, 512, 512,
                        8192 };
    for (int i = 0; i < 20; ++i) { t.src[i] = s[i]; t.off[i] = o[i]; t.cnt[i] = n[i]; }
    convert_params<<<20, 256, 0, stream>>>(t, prm, flag);
  }

  dim3 tblk(32, 8);
  auto T = [&](const void* s, u16* d, int K, int N) {
    transpose_kernel<<<dim3(N / 32, K / 32), tblk, 0, stream>>>(s, d, K, N, flag);
  };
  auto G = [&](int epi, const u16* A, const u16* Bt, const u16* bias,
               u16* ob, float* of, const u16* add, int M, int N, int K) {
    dim3 g(N / 128, M / 128), blk(256);
    switch (epi) {
      case 0: gemm_bt<0><<<g, blk, 0, stream>>>(A, Bt, bias, ob, of, add, M, N, K, flag); break;
      case 1: gemm_bt<1><<<g, blk, 0, stream>>>(A, Bt, bias, ob, of, add, M, N, K, flag); break;
      case 2: gemm_bt<2><<<g, blk, 0, stream>>>(A, Bt, bias, ob, of, add, M, N, K, flag); break;
      case 3: gemm_bt<3><<<g, blk, 0, stream>>>(A, Bt, bias, ob, of, add, M, N, K, flag); break;
      case 5: gemm_bt<5><<<g, blk, 0, stream>>>(A, Bt, bias, ob, of, add, M, N, K, flag); break;
      case 7: gemm_bt<7><<<g, blk, 0, stream>>>(A, Bt, bias, ob, of, add, M, N, K, flag); break;
    }
  };

  for (int ci = 0; ci < c; ++ci) {
    const size_t row0 = (size_t)ci * R;
    const int* tsC = tstep + row0;
    u16*   outbC = (u16*)d_out + row0 * 1024;
    float* outfC = (float*)d_out + row0 * 1024;

    // canonical bf16 copies of this chunk's activations
    convert_off<<<(R * 1024) / 256, 256, 0, stream>>>(x, row0 * 1024, xbf,
                                                      (size_t)R * 1024, flag);
    convert_off<<<(R * 128) / 256, 256, 0, stream>>>(cond_in, row0 * 128, cbf,
                                                     (size_t)R * 128, flag);

    // ---- prologue ----
    temb_kernel<<<R, 256, 0, stream>>>(tsC, hn);                    // temb -> hn
    T(t_w1, wbuf, 512, 2048);
    G(1, hn, wbuf, prm + P_t_b1, xp, nullptr, nullptr, R, 2048, 512);
    T(t_w2, wbuf, 2048, 512);
    G(0, xp, wbuf, prm + P_t_b2, cond, nullptr, nullptr, R, 512, 2048);
    T(c_w1, wbuf, 128, 512);
    G(1, cbf, wbuf, prm + P_c_b1, hn, nullptr, nullptr, R, 512, 128);
    T(c_w2, wbuf, 512, 512);
    G(3, hn, wbuf, prm + P_c_b2, cond, nullptr, cond, R, 512, 512);
    T(in_w, wbuf, 1024, 512);
    G(5, xbf, wbuf, prm + P_in_b, nullptr, h, nullptr, R, 512, 1024);

    // ---- layers ----
    for (int i = 0; i < 8; ++i) {
      transpose_layer<<<3200, tblk, 0, stream>>>(
          inproj_w, condp_w, out_w, dt_w, B_w, C_w, i, wbuf, flag);
      ln_kernel<<<R / 4, 256, 0, stream>>>(h, hn, prm + P_norm_w + i * 512,
                                           prm + P_norm_b + i * 512);
      G(0, cond, wbuf + 1048576, prm + P_condp_b + i * 1024,
        cp, nullptr, nullptr, R, 1024, 512);
      G(0, hn, wbuf, prm + P_inproj_b + i * 2048,
        xp, nullptr, nullptr, R, 2048, 512);
      fuse_conv_kernel<<<(R * 1024) / 256, 256, 0, stream>>>(
          xp, prm + P_conv_w + i * 3072, prm + P_conv_b + i * 1024, cp, xproj);
      G(0, xproj, wbuf + 2097152, nullptr,
        dtbc, nullptr, nullptr, R, 1152, 1024);
      scan_kernel<<<R / 4, 256, 0, stream>>>(
          dtbc, xproj, xp, prm + P_dt_b + i * 1024, prm + P_dt_bias + i * 1024,
          prm + P_B_b + i * 64, prm + P_C_b + i * 64, prm + P_Dp + i * 1024,
          cp /* y */);
      G(2, cp, wbuf + 1572864, prm + P_out_b + i * 512,
        nullptr, h, nullptr, R, 512, 1024);
    }

    // ---- tail ----
    ln_kernel<<<R / 4, 256, 0, stream>>>(h, hn, prm + P_on_w, prm + P_on_b);
    T(op_w, wbuf, 512, 1024);
    G(7, hn, wbuf, prm + P_op_b, outbC, outfC, nullptr, R, 1024, 512);
  }
}

// Round 5
// 3087.039 us; speedup vs baseline: 1.3222x; 1.3222x over previous
//
#include <hip/hip_runtime.h>
#include <hip/hip_bf16.h>
#include <cstdint>
#include <cstddef>

typedef unsigned short u16;
typedef __attribute__((ext_vector_type(8))) short short8;
typedef __attribute__((ext_vector_type(4))) float float4v;

__device__ __forceinline__ float b2f(u16 u) {
  union { unsigned int i; float f; } v; v.i = ((unsigned int)u) << 16; return v.f;
}
__device__ __forceinline__ u16 f2b(float f) {
  union { float f; unsigned int i; } v; v.f = f;
  unsigned int r = v.i + 0x7fffu + ((v.i >> 16) & 1u);
  return (u16)(r >> 16);
}
__device__ __forceinline__ float silu_f(float v) { return v / (1.f + __expf(-v)); }
// fast softplus: max(x,0) + log(1+exp(-|x|)) via HW exp/log (no libm log1pf)
__device__ __forceinline__ float softplus_f(float v) {
  return fmaxf(v, 0.f) + __logf(1.f + __expf(-fabsf(v)));
}
// dtype-adaptive raw-input load (element index): f32!=0 -> fp32, else bf16
__device__ __forceinline__ u16 ldx(const void* src, size_t i, int f32) {
  return f32 ? f2b(((const float*)src)[i]) : ((const u16*)src)[i];
}

#define GLD_LDS16(g, s) __builtin_amdgcn_global_load_lds( \
    (const __attribute__((address_space(1))) void*)(g),   \
    (__attribute__((address_space(3))) void*)(s), 16, 0, 0)

// Dtype probe: low u16 of fp32 words ~uniform bits (~11% valid bf16 exps);
// low u16 of a bf16 pair is a real bf16 (exp in [100,127] ~always).
// flag: 0 = bf16 inputs, 1 = fp32 inputs.
__global__ void probe_kernel(const void* w, int* flag)
{
  __shared__ int cnt;
  if (threadIdx.x == 0) cnt = 0;
  __syncthreads();
  const unsigned int* p = (const unsigned int*)w;
  int c = 0;
  for (int i = threadIdx.x; i < 1024; i += 256) {
    unsigned int lo = p[i] & 0xFFFFu;
    int e = (int)((lo >> 7) & 0xFFu);
    c += (e >= 100 && e <= 127) ? 1 : 0;
  }
  atomicAdd(&cnt, c);
  __syncthreads();
  if (threadIdx.x == 0) *flag = (cnt >= 512) ? 0 : 1;
}

// Convert the 20 small-parameter tensors into one canonical bf16 block.
struct SegTable { const void* src[20]; int off[20]; int cnt[20]; };
__global__ void convert_params(SegTable t, u16* dst, const int* flag)
{
  const int s = blockIdx.x;
  const int f32 = *flag;
  u16* d = dst + t.off[s];
  const int n = t.cnt[s];
  for (int i = threadIdx.x; i < n; i += 256) d[i] = ldx(t.src[s], i, f32);
}

// Adaptive convert with element offset: dst[i] = (bf16)src[eoff + i].
__global__ void convert_off(const void* __restrict__ src, size_t eoff,
                            u16* __restrict__ dst, size_t n,
                            const int* __restrict__ flag)
{
  const size_t i = (size_t)blockIdx.x * 256 + threadIdx.x;
  if (i < n) dst[i] = ldx(src, eoff + i, *flag);
}

struct EpiP {
  const u16* bias;    // [N] bf16 (nullable)
  u16* outb;          // bf16 out
  float* outf;        // fp32 out / accumulate
  const u16* add;     // bf16 addend (EPI 3)
  const u16* cw;      // conv_w layer slice [1024*3] (EPI 4)
  const u16* cb;      // conv_b [1024]
  const u16* cp;      // cond-proj [R,1024]
  u16* xproj;         // [R,1024] (EPI 4)
  u16* gate;          // [R,1024] (EPI 4)
  const u16* dtb;     // dt_b [1024] (EPI 6)
  const u16* dtbias;  // dt_bias [1024]
  float* dtsum;       // [R] (EPI 6, atomic accumulate; pre-zeroed)
  float* bc;          // [R,128] fp32 (EPI 6)
  const int* dtf;     // dtype flag (EPI 7)
};

// ---------------------------------------------------------------------------
// C[M,N] = epilogue(A[M,K] @ Bt[N,K]^T + bias). 128x128x32 tile, 4 waves,
// m97-lineage core. A, Bt canonical bf16.
// EPI: 0 bf16; 1 silu->bf16; 2 outf+=v; 3 (v+add)->bf16; 5 fp32;
//      4 inproj-fused: n<1024 -> xproj = silu(v*convw+convb)+cp, else gate;
//      6 dt-fused: bn<1024 -> softplus row-reduce -> atomic dtsum,
//                  bn==1024 -> raw fp32 -> bc[row,0:128];
//      7 final store, fp32 if *dtf else bf16.
// ---------------------------------------------------------------------------
template<int EPI>
__global__ __launch_bounds__(256)
void gemm_bt(const u16* __restrict__ A, const u16* __restrict__ Bt,
             EpiP e, int M, int N, int K)
{
  __shared__ u16 As[128 * 32];
  __shared__ u16 Bs[128 * 32];
  const int tid  = threadIdx.x;
  const int lane = tid & 63;
  const int wave = tid >> 6;
  const int quad = lane >> 4;
  const int l15  = lane & 15;
  const int wr = (wave >> 1) << 6;
  const int wc = (wave & 1) << 6;
  const int bm = blockIdx.y * 128;
  const int bn = blockIdx.x * 128;

  const int r0 = tid >> 2;
  const int c0 = (tid & 3) << 3;
  const u16* Ab = A  + (size_t)(bm + r0) * K + c0;
  const u16* Bb = Bt + (size_t)(bn + r0) * K + c0;
  char* sA = (char*)As + tid * 16;
  char* sB = (char*)Bs + tid * 16;

  float4v acc[4][4] = {};

  for (int k0 = 0; k0 < K; k0 += 32) {
    GLD_LDS16(Ab + k0,                  sA);
    GLD_LDS16(Ab + (size_t)64 * K + k0, sA + 4096);
    GLD_LDS16(Bb + k0,                  sB);
    GLD_LDS16(Bb + (size_t)64 * K + k0, sB + 4096);
    __syncthreads();

    short8 aF[4], bF[4];
#pragma unroll
    for (int i = 0; i < 4; ++i) {
      aF[i] = *(const short8*)(As + (wr + i * 16 + l15) * 32 + quad * 8);
      bF[i] = *(const short8*)(Bs + (wc + i * 16 + l15) * 32 + quad * 8);
    }
#pragma unroll
    for (int mi = 0; mi < 4; ++mi)
#pragma unroll
      for (int ni = 0; ni < 4; ++ni)
        acc[mi][ni] = __builtin_amdgcn_mfma_f32_16x16x32_bf16(aF[mi], bF[ni], acc[mi][ni], 0, 0, 0);
    __syncthreads();
  }

  if (EPI == 6) {
    if (bn < 1024) {  // dt columns: softplus + row partial-sum -> atomic
#pragma unroll
      for (int mi = 0; mi < 4; ++mi) {
#pragma unroll
        for (int r = 0; r < 4; ++r) {
          float s = 0.f;
#pragma unroll
          for (int ni = 0; ni < 4; ++ni) {
            const int n = bn + wc + ni * 16 + l15;
            s += softplus_f(acc[mi][ni][r] + b2f(e.dtb[n]) + b2f(e.dtbias[n]));
          }
#pragma unroll
          for (int m = 1; m < 16; m <<= 1) s += __shfl_xor(s, m);
          if (l15 == 0)
            atomicAdd(&e.dtsum[bm + wr + mi * 16 + quad * 4 + r], s);
        }
      }
    } else {  // Bp|Cp columns -> raw fp32 bc[row, 0:128]
#pragma unroll
      for (int mi = 0; mi < 4; ++mi)
#pragma unroll
        for (int ni = 0; ni < 4; ++ni) {
          const int row = bm + wr + mi * 16 + quad * 4;
          const int col = wc + ni * 16 + l15;
#pragma unroll
          for (int r = 0; r < 4; ++r)
            e.bc[(size_t)(row + r) * 128 + col] = acc[mi][ni][r];
        }
    }
    return;
  }

  float bv[4];
#pragma unroll
  for (int ni = 0; ni < 4; ++ni)
    bv[ni] = e.bias ? b2f(e.bias[bn + wc + ni * 16 + l15]) : 0.f;

  const int f32out = (EPI == 7) ? *e.dtf : 0;

#pragma unroll
  for (int mi = 0; mi < 4; ++mi) {
#pragma unroll
    for (int ni = 0; ni < 4; ++ni) {
      const int m = bm + wr + mi * 16 + quad * 4;
      const int n = bn + wc + ni * 16 + l15;
#pragma unroll
      for (int r = 0; r < 4; ++r) {
        float v = acc[mi][ni][r] + bv[ni];
        size_t idx = (size_t)(m + r) * N + n;
        if (EPI == 0)      e.outb[idx] = f2b(v);
        else if (EPI == 1) e.outb[idx] = f2b(silu_f(v));
        else if (EPI == 2) e.outf[idx] = e.outf[idx] + v;
        else if (EPI == 3) e.outb[idx] = f2b(v + b2f(e.add[idx]));
        else if (EPI == 5) e.outf[idx] = v;
        else if (EPI == 7) { if (f32out) e.outf[idx] = v; else e.outb[idx] = f2b(v); }
        else if (EPI == 4) {
          if (n < 1024) {
            float w = silu_f(v * b2f(e.cw[n * 3 + 1]) + b2f(e.cb[n]));
            size_t ix = (size_t)(m + r) * 1024 + n;
            e.xproj[ix] = f2b(w + b2f(e.cp[ix]));
          } else {
            e.gate[(size_t)(m + r) * 1024 + (n - 1024)] = f2b(v);
          }
        }
      }
    }
  }
}

// LayerNorm over D=512, fp32 in -> bf16 out; optionally zeroes dtsum[row].
__global__ __launch_bounds__(256)
void ln_kernel(const float* __restrict__ in, u16* __restrict__ out,
               const u16* __restrict__ w, const u16* __restrict__ b,
               float* __restrict__ dtsum)
{
  const int lane = threadIdx.x & 63;
  const int row  = blockIdx.x * 4 + (threadIdx.x >> 6);
  if (dtsum && lane == 0) dtsum[row] = 0.f;
  const float* x = in + (size_t)row * 512;
  float v[8], s = 0.f;
#pragma unroll
  for (int i = 0; i < 8; ++i) { v[i] = x[i * 64 + lane]; s += v[i]; }
#pragma unroll
  for (int m = 1; m < 64; m <<= 1) s += __shfl_xor(s, m);
  const float mean = s * (1.f / 512.f);
  float s2 = 0.f;
#pragma unroll
  for (int i = 0; i < 8; ++i) { float d = v[i] - mean; s2 += d * d; }
#pragma unroll
  for (int m = 1; m < 64; m <<= 1) s2 += __shfl_xor(s2, m);
  const float rs = rsqrtf(s2 * (1.f / 512.f) + 1e-5f);
  u16* o = out + (size_t)row * 512;
#pragma unroll
  for (int i = 0; i < 8; ++i) {
    int c = i * 64 + lane;
    o[c] = f2b((v[i] - mean) * rs * b2f(w[c]) + b2f(b[c]));
  }
}

// Timestep sinusoidal embedding: out[b,0:256]=cos, out[b,256:512]=sin.
__global__ void temb_kernel(const int* __restrict__ ts, u16* __restrict__ out)
{
  const int b = blockIdx.x, d = threadIdx.x;  // 256 threads
  float t = (float)ts[b];
  float fr = __expf(-9.210340371976184f * (float)d * (1.f / 256.f));
  float a = t * fr;
  out[(size_t)b * 512 + d]       = f2b(cosf(a));
  out[(size_t)b * 512 + 256 + d] = f2b(sinf(a));
}

// Selective-scan collapse (L=1):
// y = (dot(Bp,Cp)*mean(softplus_dt)*mean(x) + x*Dp) * silu(gate).
// dtsum[row] = sum softplus (from EPI6); bc[row,0:64]=Bp raw, [64:128]=Cp raw.
__global__ __launch_bounds__(256)
void scan_kernel(const float* __restrict__ bc, const float* __restrict__ dtsum,
                 const u16* __restrict__ xproj, const u16* __restrict__ gate,
                 const u16* __restrict__ B_b, const u16* __restrict__ C_b,
                 const u16* __restrict__ Dp, u16* __restrict__ y)
{
  const int lane = threadIdx.x & 63;
  const int row  = blockIdx.x * 4 + (threadIdx.x >> 6);
  const u16* xrow = xproj + (size_t)row * 1024;
  float xv[16], sx = 0.f;
#pragma unroll
  for (int i = 0; i < 16; ++i) { xv[i] = b2f(xrow[i * 64 + lane]); sx += xv[i]; }
  float bp  = bc[(size_t)row * 128 + lane]      + b2f(B_b[lane]);
  float cpv = bc[(size_t)row * 128 + 64 + lane] + b2f(C_b[lane]);
  float dot = bp * cpv;
#pragma unroll
  for (int m = 1; m < 64; m <<= 1) {
    sx  += __shfl_xor(sx, m);
    dot += __shfl_xor(dot, m);
  }
  const float scal = dot * (dtsum[row] * (1.f / 1024.f)) * (sx * (1.f / 1024.f));
  const u16* grow = gate + (size_t)row * 1024;
  u16* yrow = y + (size_t)row * 1024;
#pragma unroll
  for (int i = 0; i < 16; ++i) {
    int c = i * 64 + lane;
    yrow[c] = f2b((scal + xv[i] * b2f(Dp[c])) * silu_f(b2f(grow[c])));
  }
}

// 32x32-tiled transpose from a RAW input (adaptive): dst[n][k] = src[k][n].
__global__ void transpose_kernel(const void* __restrict__ src, u16* __restrict__ dst,
                                 int K, int N, const int* flag)
{
  __shared__ u16 t[32][33];
  const int f32 = *flag;
  const int n0 = blockIdx.x * 32, k0 = blockIdx.y * 32;
  const int tx = threadIdx.x, ty = threadIdx.y;
#pragma unroll
  for (int i = 0; i < 32; i += 8)
    t[ty + i][tx] = ldx(src, (size_t)(k0 + ty + i) * N + n0 + tx, f32);
  __syncthreads();
#pragma unroll
  for (int i = 0; i < 32; i += 8)
    dst[(size_t)(n0 + ty + i) * K + k0 + tx] = t[tx][ty + i];
}

// Segmented adaptive transpose of one layer's weights into wbuf; slice by
// ELEMENT offset (dtype width applied in ldx). grid.x = 3200.
// wbuf (u16 elems): inprojT @0 [2048,512]; condpT @1048576 [1024,512];
// outT @1572864 [512,1024]; dtbcT @2097152 [1152,1024].
__global__ void transpose_layer(const void* __restrict__ ipw, const void* __restrict__ cpw,
                                const void* __restrict__ ow, const void* __restrict__ dtw,
                                const void* __restrict__ bw, const void* __restrict__ cw_,
                                int layer, u16* __restrict__ wbuf, const int* flag)
{
  __shared__ u16 t[32][33];
  const int f32 = *flag;
  int tb_ = blockIdx.x;
  const void* src; u16* dst; int K, N; size_t eoff;
  if (tb_ < 1024)      { src = ipw; dst = wbuf;           K = 512;  N = 2048; eoff = (size_t)layer * 512 * 2048; }
  else if (tb_ < 1536) { tb_ -= 1024; src = cpw; dst = wbuf + 1048576; K = 512;  N = 1024; eoff = (size_t)layer * 512 * 1024; }
  else if (tb_ < 2048) { tb_ -= 1536; src = ow;  dst = wbuf + 1572864; K = 1024; N = 512;  eoff = (size_t)layer * 1024 * 512; }
  else if (tb_ < 3072) { tb_ -= 2048; src = dtw; dst = wbuf + 2097152; K = 1024; N = 1024; eoff = (size_t)layer * 1024 * 1024; }
  else if (tb_ < 3136) { tb_ -= 3072; src = bw;  dst = wbuf + 2097152 + 1024 * 1024; K = 1024; N = 64; eoff = (size_t)layer * 1024 * 64; }
  else                 { tb_ -= 3136; src = cw_; dst = wbuf + 2097152 + 1088 * 1024; K = 1024; N = 64; eoff = (size_t)layer * 1024 * 64; }
  const int nt = tb_ % (N / 32), kt = tb_ / (N / 32);
  const int n0 = nt * 32, k0 = kt * 32;
  const int tx = threadIdx.x, ty = threadIdx.y;
#pragma unroll
  for (int i = 0; i < 32; i += 8)
    t[ty + i][tx] = ldx(src, eoff + (size_t)(k0 + ty + i) * N + n0 + tx, f32);
  __syncthreads();
#pragma unroll
  for (int i = 0; i < 32; i += 8)
    dst[(size_t)(n0 + ty + i) * K + k0 + tx] = t[tx][ty + i];
}

// Param-block offsets (u16 elems)
enum {
  P_in_b = 0, P_t_b1 = 512, P_t_b2 = 2560, P_c_b1 = 3072, P_c_b2 = 3584,
  P_op_b = 4096, P_on_w = 5120, P_on_b = 5632, P_norm_w = 6144,
  P_norm_b = 10240, P_inproj_b = 14336, P_condp_b = 30720, P_out_b = 38912,
  P_conv_w = 43008, P_conv_b = 67584, P_dt_b = 75776, P_dt_bias = 83968,
  P_B_b = 92160, P_C_b = 92672, P_Dp = 93184, P_TOTAL = 101376
};

extern "C" void kernel_launch(void* const* d_in, const int* in_sizes, int n_in,
                              void* d_out, int out_size, void* d_ws, size_t ws_size,
                              hipStream_t stream)
{
  const void* x        = d_in[0];
  const int*  tstep    = (const int*)d_in[1];
  const void* cond_in  = d_in[2];
  const void* in_w     = d_in[3];
  const void* in_b     = d_in[4];
  const void* t_w1     = d_in[5];
  const void* t_b1     = d_in[6];
  const void* t_w2     = d_in[7];
  const void* t_b2     = d_in[8];
  const void* c_w1     = d_in[9];
  const void* c_b1     = d_in[10];
  const void* c_w2     = d_in[11];
  const void* c_b2     = d_in[12];
  const void* norm_w   = d_in[13];
  const void* norm_b   = d_in[14];
  const void* inproj_w = d_in[15];
  const void* inproj_b = d_in[16];
  const void* conv_w   = d_in[17];
  const void* conv_b   = d_in[18];
  const void* dt_w     = d_in[19];
  const void* dt_b     = d_in[20];
  const void* dt_bias  = d_in[21];
  /* d_in[22] = A_log: dead at L=1 (h0 == 0, single scan step) */
  const void* Dp       = d_in[23];
  const void* B_w      = d_in[24];
  const void* B_b      = d_in[25];
  const void* C_w      = d_in[26];
  const void* C_b      = d_in[27];
  const void* condp_w  = d_in[28];
  const void* condp_b  = d_in[29];
  const void* out_w    = d_in[30];
  const void* out_b    = d_in[31];
  const void* on_w     = d_in[32];
  const void* on_b     = d_in[33];
  const void* op_w     = d_in[34];
  const void* op_b     = d_in[35];

  const int B = 16384;
  const size_t WB = (size_t)3276800 * 2;  // 6.25 MiB weight scratch

  // per-row ws bytes: h 2048 + hn 1024 + cond 1024 + xg 4096 + cp 2048 +
  // xbf 2048 + cbf 256 + bc 512 + dtsum 4 -> 13056 (with align slack)
  int c = 128;
  for (int cc = 1; cc <= 128; cc <<= 1) {
    size_t R = (size_t)B / cc;
    if (WB + 262144 + R * 13056 + 65536 <= ws_size) { c = cc; break; }
  }
  const int R = B / c;

  char* p = (char*)d_ws;
  auto alloc = [&](size_t bytes) {
    char* r = p; p += ((bytes + 255) & ~(size_t)255); return r;
  };
  int*   flag  = (int*)alloc(4);
  u16*   prm   = (u16*)alloc((size_t)P_TOTAL * 2);
  u16*   wbuf  = (u16*)alloc(WB);
  float* h     = (float*)alloc((size_t)R * 512 * 4);
  u16*   hn    = (u16*)alloc((size_t)R * 512 * 2);
  u16*   cond  = (u16*)alloc((size_t)R * 512 * 2);
  u16*   xg    = (u16*)alloc((size_t)R * 2048 * 2);  // [xproj | gate]; also t1
  u16*   cp    = (u16*)alloc((size_t)R * 1024 * 2);
  u16*   xbf   = (u16*)alloc((size_t)R * 1024 * 2);
  u16*   cbf   = (u16*)alloc((size_t)R * 128 * 2);
  float* bc    = (float*)alloc((size_t)R * 128 * 4);
  float* dtsum = (float*)alloc((size_t)R * 4);
  u16*   xproj = xg;
  u16*   gate  = xg + (size_t)R * 1024;

  // ---- dtype probe + canonical bf16 params (once per launch) ----
  probe_kernel<<<1, 256, 0, stream>>>(in_w, flag);
  {
    SegTable t;
    const void* s[20] = { in_b, t_b1, t_b2, c_b1, c_b2, op_b, on_w, on_b,
                          norm_w, norm_b, inproj_b, condp_b, out_b, conv_w,
                          conv_b, dt_b, dt_bias, B_b, C_b, Dp };
    const int o[20] = { P_in_b, P_t_b1, P_t_b2, P_c_b1, P_c_b2, P_op_b, P_on_w,
                        P_on_b, P_norm_w, P_norm_b, P_inproj_b, P_condp_b,
                        P_out_b, P_conv_w, P_conv_b, P_dt_b, P_dt_bias, P_B_b,
                        P_C_b, P_Dp };
    const int n[20] = { 512, 2048, 512, 512, 512, 1024, 512, 512, 4096, 4096,
                        16384, 8192, 4096, 24576, 8192, 8192, 8192, 512, 512,
                        8192 };
    for (int i = 0; i < 20; ++i) { t.src[i] = s[i]; t.off[i] = o[i]; t.cnt[i] = n[i]; }
    convert_params<<<20, 256, 0, stream>>>(t, prm, flag);
  }

  dim3 tblk(32, 8);
  auto T = [&](const void* s, u16* d, int K, int N) {
    transpose_kernel<<<dim3(N / 32, K / 32), tblk, 0, stream>>>(s, d, K, N, flag);
  };
  auto G = [&](int epi, const u16* A, const u16* Bt, EpiP e, int M, int N, int K) {
    dim3 g(N / 128, M / 128), blk(256);
    switch (epi) {
      case 0: gemm_bt<0><<<g, blk, 0, stream>>>(A, Bt, e, M, N, K); break;
      case 1: gemm_bt<1><<<g, blk, 0, stream>>>(A, Bt, e, M, N, K); break;
      case 2: gemm_bt<2><<<g, blk, 0, stream>>>(A, Bt, e, M, N, K); break;
      case 3: gemm_bt<3><<<g, blk, 0, stream>>>(A, Bt, e, M, N, K); break;
      case 4: gemm_bt<4><<<g, blk, 0, stream>>>(A, Bt, e, M, N, K); break;
      case 5: gemm_bt<5><<<g, blk, 0, stream>>>(A, Bt, e, M, N, K); break;
      case 6: gemm_bt<6><<<g, blk, 0, stream>>>(A, Bt, e, M, N, K); break;
      case 7: gemm_bt<7><<<g, blk, 0, stream>>>(A, Bt, e, M, N, K); break;
    }
  };

  for (int ci = 0; ci < c; ++ci) {
    const size_t row0 = (size_t)ci * R;
    const int* tsC = tstep + row0;
    u16*   outbC = (u16*)d_out + row0 * 1024;
    float* outfC = (float*)d_out + row0 * 1024;

    // canonical bf16 copies of this chunk's activations
    convert_off<<<(R * 1024) / 256, 256, 0, stream>>>(x, row0 * 1024, xbf,
                                                      (size_t)R * 1024, flag);
    convert_off<<<(R * 128) / 256, 256, 0, stream>>>(cond_in, row0 * 128, cbf,
                                                     (size_t)R * 128, flag);

    EpiP e0 = {};

    // ---- prologue ----
    temb_kernel<<<R, 256, 0, stream>>>(tsC, hn);                    // temb -> hn
    T(t_w1, wbuf, 512, 2048);
    { EpiP e = e0; e.bias = prm + P_t_b1; e.outb = xg;
      G(1, hn, wbuf, e, R, 2048, 512); }                            // t1 = silu
    T(t_w2, wbuf, 2048, 512);
    { EpiP e = e0; e.bias = prm + P_t_b2; e.outb = cond;
      G(0, xg, wbuf, e, R, 512, 2048); }                            // temb2
    T(c_w1, wbuf, 128, 512);
    { EpiP e = e0; e.bias = prm + P_c_b1; e.outb = hn;
      G(1, cbf, wbuf, e, R, 512, 128); }                            // c1 = silu
    T(c_w2, wbuf, 512, 512);
    { EpiP e = e0; e.bias = prm + P_c_b2; e.outb = cond; e.add = cond;
      G(3, hn, wbuf, e, R, 512, 512); }                             // cond += cemb
    T(in_w, wbuf, 1024, 512);
    { EpiP e = e0; e.bias = prm + P_in_b; e.outf = h;
      G(5, xbf, wbuf, e, R, 512, 1024); }                           // h fp32

    // ---- layers ----
    for (int i = 0; i < 8; ++i) {
      transpose_layer<<<3200, tblk, 0, stream>>>(
          inproj_w, condp_w, out_w, dt_w, B_w, C_w, i, wbuf, flag);
      ln_kernel<<<R / 4, 256, 0, stream>>>(h, hn, prm + P_norm_w + i * 512,
                                           prm + P_norm_b + i * 512, dtsum);
      { EpiP e = e0; e.bias = prm + P_condp_b + i * 1024; e.outb = cp;
        G(0, cond, wbuf + 1048576, e, R, 1024, 512); }              // cond proj
      { EpiP e = e0; e.bias = prm + P_inproj_b + i * 2048;
        e.cw = prm + P_conv_w + i * 3072; e.cb = prm + P_conv_b + i * 1024;
        e.cp = cp; e.xproj = xproj; e.gate = gate;
        G(4, hn, wbuf, e, R, 2048, 512); }                          // xproj|gate
      { EpiP e = e0; e.dtb = prm + P_dt_b + i * 1024;
        e.dtbias = prm + P_dt_bias + i * 1024; e.dtsum = dtsum; e.bc = bc;
        G(6, xproj, wbuf + 2097152, e, R, 1152, 1024); }            // dtsum|bc
      scan_kernel<<<R / 4, 256, 0, stream>>>(
          bc, dtsum, xproj, gate, prm + P_B_b + i * 64, prm + P_C_b + i * 64,
          prm + P_Dp + i * 1024, cp /* y */);
      { EpiP e = e0; e.bias = prm + P_out_b + i * 512; e.outf = h;
        G(2, cp, wbuf + 1572864, e, R, 512, 1024); }                // h += y@W
    }

    // ---- tail ----
    ln_kernel<<<R / 4, 256, 0, stream>>>(h, hn, prm + P_on_w, prm + P_on_b,
                                         nullptr);
    T(op_w, wbuf, 512, 1024);
    { EpiP e = e0; e.bias = prm + P_op_b; e.outb = outbC; e.outf = outfC;
      e.dtf = flag;
      G(7, hn, wbuf, e, R, 1024, 512); }                            // final proj
  }
}

// Round 6
// 2804.782 us; speedup vs baseline: 1.4553x; 1.1006x over previous
//
#include <hip/hip_runtime.h>
#include <hip/hip_bf16.h>
#include <cstdint>
#include <cstddef>

typedef unsigned short u16;
typedef __attribute__((ext_vector_type(8))) short short8;
typedef __attribute__((ext_vector_type(4))) float float4v;

__device__ __forceinline__ float b2f(u16 u) {
  union { unsigned int i; float f; } v; v.i = ((unsigned int)u) << 16; return v.f;
}
__device__ __forceinline__ u16 f2b(float f) {
  union { float f; unsigned int i; } v; v.f = f;
  unsigned int r = v.i + 0x7fffu + ((v.i >> 16) & 1u);
  return (u16)(r >> 16);
}
__device__ __forceinline__ float silu_f(float v) { return v / (1.f + __expf(-v)); }
// fast softplus: max(x,0) + log(1+exp(-|x|)) via HW exp/log
__device__ __forceinline__ float softplus_f(float v) {
  return fmaxf(v, 0.f) + __logf(1.f + __expf(-fabsf(v)));
}
// dtype-adaptive raw-input load (element index): f32!=0 -> fp32, else bf16
__device__ __forceinline__ u16 ldx(const void* src, size_t i, int f32) {
  return f32 ? f2b(((const float*)src)[i]) : ((const u16*)src)[i];
}

#define GLD_LDS16(g, s) __builtin_amdgcn_global_load_lds( \
    (const __attribute__((address_space(1))) void*)(g),   \
    (__attribute__((address_space(3))) void*)(s), 16, 0, 0)

// Dtype probe: flag 0 = bf16 inputs, 1 = fp32 inputs.
__global__ void probe_kernel(const void* w, int* flag)
{
  __shared__ int cnt;
  if (threadIdx.x == 0) cnt = 0;
  __syncthreads();
  const unsigned int* p = (const unsigned int*)w;
  int c = 0;
  for (int i = threadIdx.x; i < 1024; i += 256) {
    unsigned int lo = p[i] & 0xFFFFu;
    int e = (int)((lo >> 7) & 0xFFu);
    c += (e >= 100 && e <= 127) ? 1 : 0;
  }
  atomicAdd(&cnt, c);
  __syncthreads();
  if (threadIdx.x == 0) *flag = (cnt >= 512) ? 0 : 1;
}

// Convert the 20 small-parameter tensors into one canonical bf16 block.
struct SegTable { const void* src[20]; int off[20]; int cnt[20]; };
__global__ void convert_params(SegTable t, u16* dst, const int* flag)
{
  const int s = blockIdx.x;
  const int f32 = *flag;
  u16* d = dst + t.off[s];
  const int n = t.cnt[s];
  for (int i = threadIdx.x; i < n; i += 256) d[i] = ldx(t.src[s], i, f32);
}

// Adaptive convert with element offset: dst[i] = (bf16)src[eoff + i].
__global__ void convert_off(const void* __restrict__ src, size_t eoff,
                            u16* __restrict__ dst, size_t n,
                            const int* __restrict__ flag)
{
  const size_t i = (size_t)blockIdx.x * 256 + threadIdx.x;
  if (i < n) dst[i] = ldx(src, eoff + i, *flag);
}

struct EpiP {
  const u16* bias;    // [N] bf16 (nullable)
  u16* outb;          // bf16 out
  float* outf;        // fp32 out / accumulate
  const u16* add;     // bf16 addend (EPI 3)
  const u16* cw;      // conv_w layer slice [1024*3] (EPI 4)
  const u16* cb;      // conv_b [1024]
  const u16* cp;      // cond-proj [R,1024]
  u16* xproj;         // [R,1024] (EPI 4)
  u16* gate;          // [R,1024] (EPI 4)
  const u16* dtb;     // dt_b [1024] (EPI 6)
  const u16* dtbias;  // dt_bias [1024]
  float* dtsum;       // [R] (EPI 6, atomic accumulate; pre-zeroed)
  float* bc;          // [R,128] fp32 (EPI 6)
  const int* dtf;     // dtype flag (EPI 7)
};

// ---------------------------------------------------------------------------
// C[M,N] = epilogue(A[M,K] @ Bt[N,K]^T + bias). 128x128x32 tile, 4 waves.
// 1D grid with XCD-aware swizzle: xcd = flat & 7 owns NBM/8 row-tiles x all
// column-tiles -> per-XCD L2 holds one A-slice (kills cross-XCD A re-fetch).
// bf16-store epilogues (0/1/3/4) are LDS-staged: stage 16x64 fp32 wave-tile,
// read back row-major, 16 B/lane stores (64 lanes = 1 KB contiguous -> full
// 64-B write granules; cp/add reads coalesce too).
// EPI: 0 bf16; 1 silu->bf16; 2 outf+=v; 3 (v+add)->bf16; 5 fp32;
//      4 inproj-fused (xproj|gate); 6 dt-fused (dtsum|bc); 7 final store.
// ---------------------------------------------------------------------------
template<int EPI>
__global__ __launch_bounds__(256)
void gemm_bt(const u16* __restrict__ A, const u16* __restrict__ Bt,
             EpiP e, int M, int N, int K)
{
  __shared__ u16 S[8704];             // 17408 B: As 8K | Bs 8K; aliased stage
  u16* As = S;
  u16* Bs = S + 4096;
  const int tid  = threadIdx.x;
  const int lane = tid & 63;
  const int wave = tid >> 6;
  const int quad = lane >> 4;
  const int l15  = lane & 15;
  const int wr = (wave >> 1) << 6;
  const int wc = (wave & 1) << 6;

  // XCD-aware swizzle (bijective); NBM always multiple of 8 here.
  const int NBN = N >> 7, NBM = M >> 7;
  int bm, bn;
  {
    const int flat = blockIdx.x;
    if ((NBM & 7) == 0) {
      const int xcd = flat & 7;
      const int s = flat >> 3;
      bn = (s % NBN) << 7;
      bm = (xcd * (NBM >> 3) + s / NBN) << 7;
    } else {
      bn = (flat % NBN) << 7;
      bm = (flat / NBN) << 7;
    }
  }

  const int r0 = tid >> 2;
  const int c0 = (tid & 3) << 3;
  const u16* Ab = A  + (size_t)(bm + r0) * K + c0;
  const u16* Bb = Bt + (size_t)(bn + r0) * K + c0;
  char* sA = (char*)As + tid * 16;
  char* sB = (char*)Bs + tid * 16;

  float4v acc[4][4] = {};

  for (int k0 = 0; k0 < K; k0 += 32) {
    GLD_LDS16(Ab + k0,                  sA);
    GLD_LDS16(Ab + (size_t)64 * K + k0, sA + 4096);
    GLD_LDS16(Bb + k0,                  sB);
    GLD_LDS16(Bb + (size_t)64 * K + k0, sB + 4096);
    __syncthreads();

    short8 aF[4], bF[4];
#pragma unroll
    for (int i = 0; i < 4; ++i) {
      aF[i] = *(const short8*)(As + (wr + i * 16 + l15) * 32 + quad * 8);
      bF[i] = *(const short8*)(Bs + (wc + i * 16 + l15) * 32 + quad * 8);
    }
#pragma unroll
    for (int mi = 0; mi < 4; ++mi)
#pragma unroll
      for (int ni = 0; ni < 4; ++ni)
        acc[mi][ni] = __builtin_amdgcn_mfma_f32_16x16x32_bf16(aF[mi], bF[ni], acc[mi][ni], 0, 0, 0);
    __syncthreads();
  }

  if (EPI == 6) {
    if (bn < 1024) {  // dt columns: softplus + row partial-sum -> atomic
#pragma unroll
      for (int mi = 0; mi < 4; ++mi) {
#pragma unroll
        for (int r = 0; r < 4; ++r) {
          float s = 0.f;
#pragma unroll
          for (int ni = 0; ni < 4; ++ni) {
            const int n = bn + wc + ni * 16 + l15;
            s += softplus_f(acc[mi][ni][r] + b2f(e.dtb[n]) + b2f(e.dtbias[n]));
          }
#pragma unroll
          for (int m = 1; m < 16; m <<= 1) s += __shfl_xor(s, m);
          if (l15 == 0)
            atomicAdd(&e.dtsum[bm + wr + mi * 16 + quad * 4 + r], s);
        }
      }
    } else {  // Bp|Cp columns -> raw fp32 bc[row, 0:128]
#pragma unroll
      for (int mi = 0; mi < 4; ++mi)
#pragma unroll
        for (int ni = 0; ni < 4; ++ni) {
          const int row = bm + wr + mi * 16 + quad * 4;
          const int col = wc + ni * 16 + l15;
#pragma unroll
          for (int r = 0; r < 4; ++r)
            e.bc[(size_t)(row + r) * 128 + col] = acc[mi][ni][r];
        }
    }
    return;
  }

  float bv[4];
#pragma unroll
  for (int ni = 0; ni < 4; ++ni)
    bv[ni] = e.bias ? b2f(e.bias[bn + wc + ni * 16 + l15]) : 0.f;

  if (EPI == 0 || EPI == 1 || EPI == 3 || EPI == 4) {
    // LDS-staged coalesced epilogue. After the final __syncthreads() the
    // LDS is free; each wave stages into its private 16x68-float region
    // (stride 68: 16B-aligned rows, 2-way-max bank aliasing).
    float* stg = (float*)S + wave * 1088;
    const int rrow = lane >> 3;         // 0..7
    const int ccol = (lane & 7) << 3;   // 0,8,..,56
#pragma unroll
    for (int mi = 0; mi < 4; ++mi) {
#pragma unroll
      for (int ni = 0; ni < 4; ++ni)
#pragma unroll
        for (int r = 0; r < 4; ++r)
          stg[(quad * 4 + r) * 68 + ni * 16 + l15] = acc[mi][ni][r] + bv[ni];
      // same-wave LDS ordering: reads below depend on writes above
#pragma unroll
      for (int half = 0; half < 2; ++half) {
        const int lrow = rrow + half * 8;
        const int gm = bm + wr + mi * 16 + lrow;
        const int gn = bn + wc + ccol;
        float vv[8];
#pragma unroll
        for (int j = 0; j < 8; ++j) vv[j] = stg[lrow * 68 + ccol + j];
        u16 ov[8];
        u16* dst;
        if (EPI == 0) {
#pragma unroll
          for (int j = 0; j < 8; ++j) ov[j] = f2b(vv[j]);
          dst = e.outb + (size_t)gm * N + gn;
        } else if (EPI == 1) {
#pragma unroll
          for (int j = 0; j < 8; ++j) ov[j] = f2b(silu_f(vv[j]));
          dst = e.outb + (size_t)gm * N + gn;
        } else if (EPI == 3) {
          const u16* ar = e.add + (size_t)gm * N + gn;
#pragma unroll
          for (int j = 0; j < 8; ++j) ov[j] = f2b(vv[j] + b2f(ar[j]));
          dst = e.outb + (size_t)gm * N + gn;
        } else {  // EPI 4: whole 8-col chunk is on one side of 1024
          if (gn < 1024) {
            const size_t ix = (size_t)gm * 1024 + gn;
            const u16* cr = e.cp + ix;
#pragma unroll
            for (int j = 0; j < 8; ++j) {
              float w = silu_f(vv[j] * b2f(e.cw[(gn + j) * 3 + 1]) +
                               b2f(e.cb[gn + j]));
              ov[j] = f2b(w + b2f(cr[j]));
            }
            dst = e.xproj + ix;
          } else {
            const size_t ix = (size_t)gm * 1024 + (gn - 1024);
#pragma unroll
            for (int j = 0; j < 8; ++j) ov[j] = f2b(vv[j]);
            dst = e.gate + ix;
          }
        }
        *(short8*)dst = *(const short8*)ov;
      }
    }
    return;
  }

  const int f32out = (EPI == 7) ? *e.dtf : 0;
#pragma unroll
  for (int mi = 0; mi < 4; ++mi) {
#pragma unroll
    for (int ni = 0; ni < 4; ++ni) {
      const int m = bm + wr + mi * 16 + quad * 4;
      const int n = bn + wc + ni * 16 + l15;
#pragma unroll
      for (int r = 0; r < 4; ++r) {
        float v = acc[mi][ni][r] + bv[ni];
        size_t idx = (size_t)(m + r) * N + n;
        if (EPI == 2)      e.outf[idx] = e.outf[idx] + v;
        else if (EPI == 5) e.outf[idx] = v;
        else if (EPI == 7) { if (f32out) e.outf[idx] = v; else e.outb[idx] = f2b(v); }
      }
    }
  }
}

// LayerNorm over D=512, fp32 in -> bf16 out; optionally zeroes dtsum[row].
__global__ __launch_bounds__(256)
void ln_kernel(const float* __restrict__ in, u16* __restrict__ out,
               const u16* __restrict__ w, const u16* __restrict__ b,
               float* __restrict__ dtsum)
{
  const int lane = threadIdx.x & 63;
  const int row  = blockIdx.x * 4 + (threadIdx.x >> 6);
  if (dtsum && lane == 0) dtsum[row] = 0.f;
  const float* x = in + (size_t)row * 512;
  float v[8], s = 0.f;
#pragma unroll
  for (int i = 0; i < 8; ++i) { v[i] = x[i * 64 + lane]; s += v[i]; }
#pragma unroll
  for (int m = 1; m < 64; m <<= 1) s += __shfl_xor(s, m);
  const float mean = s * (1.f / 512.f);
  float s2 = 0.f;
#pragma unroll
  for (int i = 0; i < 8; ++i) { float d = v[i] - mean; s2 += d * d; }
#pragma unroll
  for (int m = 1; m < 64; m <<= 1) s2 += __shfl_xor(s2, m);
  const float rs = rsqrtf(s2 * (1.f / 512.f) + 1e-5f);
  u16* o = out + (size_t)row * 512;
#pragma unroll
  for (int i = 0; i < 8; ++i) {
    int c = i * 64 + lane;
    o[c] = f2b((v[i] - mean) * rs * b2f(w[c]) + b2f(b[c]));
  }
}

// Timestep sinusoidal embedding: out[b,0:256]=cos, out[b,256:512]=sin.
__global__ void temb_kernel(const int* __restrict__ ts, u16* __restrict__ out)
{
  const int b = blockIdx.x, d = threadIdx.x;  // 256 threads
  float t = (float)ts[b];
  float fr = __expf(-9.210340371976184f * (float)d * (1.f / 256.f));
  float a = t * fr;
  out[(size_t)b * 512 + d]       = f2b(cosf(a));
  out[(size_t)b * 512 + 256 + d] = f2b(sinf(a));
}

// Selective-scan collapse (L=1):
// y = (dot(Bp,Cp)*mean(softplus_dt)*mean(x) + x*Dp) * silu(gate).
__global__ __launch_bounds__(256)
void scan_kernel(const float* __restrict__ bc, const float* __restrict__ dtsum,
                 const u16* __restrict__ xproj, const u16* __restrict__ gate,
                 const u16* __restrict__ B_b, const u16* __restrict__ C_b,
                 const u16* __restrict__ Dp, u16* __restrict__ y)
{
  const int lane = threadIdx.x & 63;
  const int row  = blockIdx.x * 4 + (threadIdx.x >> 6);
  const u16* xrow = xproj + (size_t)row * 1024;
  float xv[16], sx = 0.f;
#pragma unroll
  for (int i = 0; i < 16; ++i) { xv[i] = b2f(xrow[i * 64 + lane]); sx += xv[i]; }
  float bp  = bc[(size_t)row * 128 + lane]      + b2f(B_b[lane]);
  float cpv = bc[(size_t)row * 128 + 64 + lane] + b2f(C_b[lane]);
  float dot = bp * cpv;
#pragma unroll
  for (int m = 1; m < 64; m <<= 1) {
    sx  += __shfl_xor(sx, m);
    dot += __shfl_xor(dot, m);
  }
  const float scal = dot * (dtsum[row] * (1.f / 1024.f)) * (sx * (1.f / 1024.f));
  const u16* grow = gate + (size_t)row * 1024;
  u16* yrow = y + (size_t)row * 1024;
#pragma unroll
  for (int i = 0; i < 16; ++i) {
    int c = i * 64 + lane;
    yrow[c] = f2b((scal + xv[i] * b2f(Dp[c])) * silu_f(b2f(grow[c])));
  }
}

// 32x32-tiled transpose from a RAW input (adaptive): dst[n][k] = src[k][n].
__global__ void transpose_kernel(const void* __restrict__ src, u16* __restrict__ dst,
                                 int K, int N, const int* flag)
{
  __shared__ u16 t[32][33];
  const int f32 = *flag;
  const int n0 = blockIdx.x * 32, k0 = blockIdx.y * 32;
  const int tx = threadIdx.x, ty = threadIdx.y;
#pragma unroll
  for (int i = 0; i < 32; i += 8)
    t[ty + i][tx] = ldx(src, (size_t)(k0 + ty + i) * N + n0 + tx, f32);
  __syncthreads();
#pragma unroll
  for (int i = 0; i < 32; i += 8)
    dst[(size_t)(n0 + ty + i) * K + k0 + tx] = t[tx][ty + i];
}

// Segmented adaptive transpose of one layer's weights into wbuf; slice by
// ELEMENT offset (dtype width applied in ldx). grid.x = 3200.
// wbuf (u16 elems): inprojT @0 [2048,512]; condpT @1048576 [1024,512];
// outT @1572864 [512,1024]; dtbcT @2097152 [1152,1024].
__global__ void transpose_layer(const void* __restrict__ ipw, const void* __restrict__ cpw,
                                const void* __restrict__ ow, const void* __restrict__ dtw,
                                const void* __restrict__ bw, const void* __restrict__ cw_,
                                int layer, u16* __restrict__ wbuf, const int* flag)
{
  __shared__ u16 t[32][33];
  const int f32 = *flag;
  int tb_ = blockIdx.x;
  const void* src; u16* dst; int K, N; size_t eoff;
  if (tb_ < 1024)      { src = ipw; dst = wbuf;           K = 512;  N = 2048; eoff = (size_t)layer * 512 * 2048; }
  else if (tb_ < 1536) { tb_ -= 1024; src = cpw; dst = wbuf + 1048576; K = 512;  N = 1024; eoff = (size_t)layer * 512 * 1024; }
  else if (tb_ < 2048) { tb_ -= 1536; src = ow;  dst = wbuf + 1572864; K = 1024; N = 512;  eoff = (size_t)layer * 1024 * 512; }
  else if (tb_ < 3072) { tb_ -= 2048; src = dtw; dst = wbuf + 2097152; K = 1024; N = 1024; eoff = (size_t)layer * 1024 * 1024; }
  else if (tb_ < 3136) { tb_ -= 3072; src = bw;  dst = wbuf + 2097152 + 1024 * 1024; K = 1024; N = 64; eoff = (size_t)layer * 1024 * 64; }
  else                 { tb_ -= 3136; src = cw_; dst = wbuf + 2097152 + 1088 * 1024; K = 1024; N = 64; eoff = (size_t)layer * 1024 * 64; }
  const int nt = tb_ % (N / 32), kt = tb_ / (N / 32);
  const int n0 = nt * 32, k0 = kt * 32;
  const int tx = threadIdx.x, ty = threadIdx.y;
#pragma unroll
  for (int i = 0; i < 32; i += 8)
    t[ty + i][tx] = ldx(src, eoff + (size_t)(k0 + ty + i) * N + n0 + tx, f32);
  __syncthreads();
#pragma unroll
  for (int i = 0; i < 32; i += 8)
    dst[(size_t)(n0 + ty + i) * K + k0 + tx] = t[tx][ty + i];
}

// Param-block offsets (u16 elems)
enum {
  P_in_b = 0, P_t_b1 = 512, P_t_b2 = 2560, P_c_b1 = 3072, P_c_b2 = 3584,
  P_op_b = 4096, P_on_w = 5120, P_on_b = 5632, P_norm_w = 6144,
  P_norm_b = 10240, P_inproj_b = 14336, P_condp_b = 30720, P_out_b = 38912,
  P_conv_w = 43008, P_conv_b = 67584, P_dt_b = 75776, P_dt_bias = 83968,
  P_B_b = 92160, P_C_b = 92672, P_Dp = 93184, P_TOTAL = 101376
};

extern "C" void kernel_launch(void* const* d_in, const int* in_sizes, int n_in,
                              void* d_out, int out_size, void* d_ws, size_t ws_size,
                              hipStream_t stream)
{
  const void* x        = d_in[0];
  const int*  tstep    = (const int*)d_in[1];
  const void* cond_in  = d_in[2];
  const void* in_w     = d_in[3];
  const void* in_b     = d_in[4];
  const void* t_w1     = d_in[5];
  const void* t_b1     = d_in[6];
  const void* t_w2     = d_in[7];
  const void* t_b2     = d_in[8];
  const void* c_w1     = d_in[9];
  const void* c_b1     = d_in[10];
  const void* c_w2     = d_in[11];
  const void* c_b2     = d_in[12];
  const void* norm_w   = d_in[13];
  const void* norm_b   = d_in[14];
  const void* inproj_w = d_in[15];
  const void* inproj_b = d_in[16];
  const void* conv_w   = d_in[17];
  const void* conv_b   = d_in[18];
  const void* dt_w     = d_in[19];
  const void* dt_b     = d_in[20];
  const void* dt_bias  = d_in[21];
  /* d_in[22] = A_log: dead at L=1 (h0 == 0, single scan step) */
  const void* Dp       = d_in[23];
  const void* B_w      = d_in[24];
  const void* B_b      = d_in[25];
  const void* C_w      = d_in[26];
  const void* C_b      = d_in[27];
  const void* condp_w  = d_in[28];
  const void* condp_b  = d_in[29];
  const void* out_w    = d_in[30];
  const void* out_b    = d_in[31];
  const void* on_w     = d_in[32];
  const void* on_b     = d_in[33];
  const void* op_w     = d_in[34];
  const void* op_b     = d_in[35];

  const int B = 16384;
  const size_t WB = (size_t)3276800 * 2;  // 6.25 MiB weight scratch

  int c = 128;
  for (int cc = 1; cc <= 128; cc <<= 1) {
    size_t R = (size_t)B / cc;
    if (WB + 262144 + R * 13056 + 65536 <= ws_size) { c = cc; break; }
  }
  const int R = B / c;

  char* p = (char*)d_ws;
  auto alloc = [&](size_t bytes) {
    char* r = p; p += ((bytes + 255) & ~(size_t)255); return r;
  };
  int*   flag  = (int*)alloc(4);
  u16*   prm   = (u16*)alloc((size_t)P_TOTAL * 2);
  u16*   wbuf  = (u16*)alloc(WB);
  float* h     = (float*)alloc((size_t)R * 512 * 4);
  u16*   hn    = (u16*)alloc((size_t)R * 512 * 2);
  u16*   cond  = (u16*)alloc((size_t)R * 512 * 2);
  u16*   xg    = (u16*)alloc((size_t)R * 2048 * 2);  // [xproj | gate]; also t1
  u16*   cp    = (u16*)alloc((size_t)R * 1024 * 2);
  u16*   xbf   = (u16*)alloc((size_t)R * 1024 * 2);
  u16*   cbf   = (u16*)alloc((size_t)R * 128 * 2);
  float* bc    = (float*)alloc((size_t)R * 128 * 4);
  float* dtsum = (float*)alloc((size_t)R * 4);
  u16*   xproj = xg;
  u16*   gate  = xg + (size_t)R * 1024;

  // ---- dtype probe + canonical bf16 params (once per launch) ----
  probe_kernel<<<1, 256, 0, stream>>>(in_w, flag);
  {
    SegTable t;
    const void* s[20] = { in_b, t_b1, t_b2, c_b1, c_b2, op_b, on_w, on_b,
                          norm_w, norm_b, inproj_b, condp_b, out_b, conv_w,
                          conv_b, dt_b, dt_bias, B_b, C_b, Dp };
    const int o[20] = { P_in_b, P_t_b1, P_t_b2, P_c_b1, P_c_b2, P_op_b, P_on_w,
                        P_on_b, P_norm_w, P_norm_b, P_inproj_b, P_condp_b,
                        P_out_b, P_conv_w, P_conv_b, P_dt_b, P_dt_bias, P_B_b,
                        P_C_b, P_Dp };
    const int n[20] = { 512, 2048, 512, 512, 512, 1024, 512, 512, 4096, 4096,
                        16384, 8192, 4096, 24576, 8192, 8192, 8192, 512, 512,
                        8192 };
    for (int i = 0; i < 20; ++i) { t.src[i] = s[i]; t.off[i] = o[i]; t.cnt[i] = n[i]; }
    convert_params<<<20, 256, 0, stream>>>(t, prm, flag);
  }

  dim3 tblk(32, 8);
  auto T = [&](const void* s, u16* d, int K, int N) {
    transpose_kernel<<<dim3(N / 32, K / 32), tblk, 0, stream>>>(s, d, K, N, flag);
  };
  auto G = [&](int epi, const u16* A, const u16* Bt, EpiP e, int M, int N, int K) {
    dim3 g((N / 128) * (M / 128)), blk(256);
    switch (epi) {
      case 0: gemm_bt<0><<<g, blk, 0, stream>>>(A, Bt, e, M, N, K); break;
      case 1: gemm_bt<1><<<g, blk, 0, stream>>>(A, Bt, e, M, N, K); break;
      case 2: gemm_bt<2><<<g, blk, 0, stream>>>(A, Bt, e, M, N, K); break;
      case 3: gemm_bt<3><<<g, blk, 0, stream>>>(A, Bt, e, M, N, K); break;
      case 4: gemm_bt<4><<<g, blk, 0, stream>>>(A, Bt, e, M, N, K); break;
      case 5: gemm_bt<5><<<g, blk, 0, stream>>>(A, Bt, e, M, N, K); break;
      case 6: gemm_bt<6><<<g, blk, 0, stream>>>(A, Bt, e, M, N, K); break;
      case 7: gemm_bt<7><<<g, blk, 0, stream>>>(A, Bt, e, M, N, K); break;
    }
  };

  for (int ci = 0; ci < c; ++ci) {
    const size_t row0 = (size_t)ci * R;
    const int* tsC = tstep + row0;
    u16*   outbC = (u16*)d_out + row0 * 1024;
    float* outfC = (float*)d_out + row0 * 1024;

    // canonical bf16 copies of this chunk's activations
    convert_off<<<(R * 1024) / 256, 256, 0, stream>>>(x, row0 * 1024, xbf,
                                                      (size_t)R * 1024, flag);
    convert_off<<<(R * 128) / 256, 256, 0, stream>>>(cond_in, row0 * 128, cbf,
                                                     (size_t)R * 128, flag);

    EpiP e0 = {};

    // ---- prologue ----
    temb_kernel<<<R, 256, 0, stream>>>(tsC, hn);                    // temb -> hn
    T(t_w1, wbuf, 512, 2048);
    { EpiP e = e0; e.bias = prm + P_t_b1; e.outb = xg;
      G(1, hn, wbuf, e, R, 2048, 512); }                            // t1 = silu
    T(t_w2, wbuf, 2048, 512);
    { EpiP e = e0; e.bias = prm + P_t_b2; e.outb = cond;
      G(0, xg, wbuf, e, R, 512, 2048); }                            // temb2
    T(c_w1, wbuf, 128, 512);
    { EpiP e = e0; e.bias = prm + P_c_b1; e.outb = hn;
      G(1, cbf, wbuf, e, R, 512, 128); }                            // c1 = silu
    T(c_w2, wbuf, 512, 512);
    { EpiP e = e0; e.bias = prm + P_c_b2; e.outb = cond; e.add = cond;
      G(3, hn, wbuf, e, R, 512, 512); }                             // cond += cemb
    T(in_w, wbuf, 1024, 512);
    { EpiP e = e0; e.bias = prm + P_in_b; e.outf = h;
      G(5, xbf, wbuf, e, R, 512, 1024); }                           // h fp32

    // ---- layers ----
    for (int i = 0; i < 8; ++i) {
      transpose_layer<<<3200, tblk, 0, stream>>>(
          inproj_w, condp_w, out_w, dt_w, B_w, C_w, i, wbuf, flag);
      ln_kernel<<<R / 4, 256, 0, stream>>>(h, hn, prm + P_norm_w + i * 512,
                                           prm + P_norm_b + i * 512, dtsum);
      { EpiP e = e0; e.bias = prm + P_condp_b + i * 1024; e.outb = cp;
        G(0, cond, wbuf + 1048576, e, R, 1024, 512); }              // cond proj
      { EpiP e = e0; e.bias = prm + P_inproj_b + i * 2048;
        e.cw = prm + P_conv_w + i * 3072; e.cb = prm + P_conv_b + i * 1024;
        e.cp = cp; e.xproj = xproj; e.gate = gate;
        G(4, hn, wbuf, e, R, 2048, 512); }                          // xproj|gate
      { EpiP e = e0; e.dtb = prm + P_dt_b + i * 1024;
        e.dtbias = prm + P_dt_bias + i * 1024; e.dtsum = dtsum; e.bc = bc;
        G(6, xproj, wbuf + 2097152, e, R, 1152, 1024); }            // dtsum|bc
      scan_kernel<<<R / 4, 256, 0, stream>>>(
          bc, dtsum, xproj, gate, prm + P_B_b + i * 64, prm + P_C_b + i * 64,
          prm + P_Dp + i * 1024, cp /* y */);
      { EpiP e = e0; e.bias = prm + P_out_b + i * 512; e.outf = h;
        G(2, cp, wbuf + 1572864, e, R, 512, 1024); }                // h += y@W
    }

    // ---- tail ----
    ln_kernel<<<R / 4, 256, 0, stream>>>(h, hn, prm + P_on_w, prm + P_on_b,
                                         nullptr);
    T(op_w, wbuf, 512, 1024);
    { EpiP e = e0; e.bias = prm + P_op_b; e.outb = outbC; e.outf = outfC;
      e.dtf = flag;
      G(7, hn, wbuf, e, R, 1024, 512); }                            // final proj
  }
}